// Round 13
// baseline (4856.871 us; speedup 1.0000x reference)
//
#include <hip/hip_runtime.h>
#include <stdint.h>

// RTRBM CD-1: bit-exact replication of the JAX-CPU reference.
// Phase A: wv_gemm — XCD-swizzled, HT_A=20, launch_bounds(256,4) (r12).
// Phase B: hidden_quad — block = (col-group cg of 4 cols, h-quarter q of 128).
//          Lanes interleave the 2 b-pair workers (cp) so adjacent lanes load
//          the SAME U element (hardware broadcast -> U L2 traffic halves).
//          3-partner relaxed-atomic r exchange (same recipe as r11/r12).
// Phase E: expand bits -> out_r floats.
// Phase C: visible_big — spill fix + XCD swizzle (r12).
// Sizes: V=784, H=500, T=256, B=256. RNG: threefry partitionable.
// Eigen MT blocking (AVX no-FMA jaxlib): kc=288. K=784 -> [288,288,208]; K=500 -> [288,212].
#define NV 784
#define NH 500
#define TT 256
#define BB 256
#define NBG 128   // b-pairs

typedef float f2v __attribute__((ext_vector_type(2)));

// ---------------- threefry2x32 (JAX PRNG), exact ----------------
__device__ __forceinline__ void tf2x32(uint32_t ks0, uint32_t ks1,
                                       uint32_t x0, uint32_t x1,
                                       uint32_t& y0, uint32_t& y1) {
  uint32_t ks2 = ks0 ^ ks1 ^ 0x1BD11BDAu;
  x0 += ks0; x1 += ks1;
#define TFROT(r) { x0 += x1; x1 = (x1 << (r)) | (x1 >> (32 - (r))); x1 ^= x0; }
  TFROT(13) TFROT(15) TFROT(26) TFROT(6)
  x0 += ks1; x1 += ks2 + 1u;
  TFROT(17) TFROT(29) TFROT(16) TFROT(24)
  x0 += ks2; x1 += ks0 + 2u;
  TFROT(13) TFROT(15) TFROT(26) TFROT(6)
  x0 += ks0; x1 += ks1 + 3u;
  TFROT(17) TFROT(29) TFROT(16) TFROT(24)
  x0 += ks1; x1 += ks2 + 4u;
  TFROT(13) TFROT(15) TFROT(26) TFROT(6)
  x0 += ks2; x1 += ks0 + 5u;
#undef TFROT
  y0 = x0; y1 = x1;
}

__device__ __forceinline__ float jax_uniform(uint32_t bits) {
#pragma clang fp contract(off)
  float f = __uint_as_float((bits >> 9) | 0x3F800000u);
  return f - 1.0f;
}

// PARTITIONABLE random_bits, 32-bit: bits[j] = y0 ^ y1 of threefry(key; 0, j)
__device__ __forceinline__ uint32_t draw_bits(uint32_t k0, uint32_t k1,
                                              uint32_t j) {
  uint32_t y0, y1;
  tf2x32(k0, k1, 0u, j, y0, y1);
  return y0 ^ y1;
}

// ---------------- XLA CPU exp (Cephes/Eigen poly, no FMA) ----------------
__device__ __forceinline__ float xla_expf(float x) {
#pragma clang fp contract(off)
  float xc = fminf(fmaxf(x, -88.3762626647949f), 88.3762626647950f);
  float fx = floorf(xc * 1.44269504088896341f + 0.5f);
  float tmp = 0.693359375f * fx;
  float z = -2.12194440e-4f * fx;
  float xr = xc - tmp;
  xr = xr - z;
  z = xr * xr;
  float y = xr * 1.9875691500e-4f + 1.3981999507e-3f;
  y = y * xr + 8.3334519073e-3f;
  y = y * xr + 4.1665795894e-2f;
  y = y * xr + 1.6666665459e-1f;
  y = y * xr + 5.0000001201e-1f;
  y = y * z + xr;
  y = 1.0f + y;
  int e = (int)fx;
  float pow2 = __int_as_float((uint32_t)(e + 127) << 23);
  return y * pow2;
}

__device__ __forceinline__ float xla_sigmoid(float x) {
#pragma clang fp contract(off)
  float e = xla_expf(-x);
  float d = 1.0f + e;
  return 1.0f / d;
}

// even-bit compress: 64-bit mask -> 32 bits taken from even lane positions
__device__ __forceinline__ uint32_t extract_even(unsigned long long x) {
  x &= 0x5555555555555555ull;
  x = (x ^ (x >> 1)) & 0x3333333333333333ull;
  x = (x ^ (x >> 2)) & 0x0F0F0F0F0F0F0F0Full;
  x = (x ^ (x >> 4)) & 0x00FF00FF00FF00FFull;
  x = (x ^ (x >> 8)) & 0x0000FFFF0000FFFFull;
  x = (x ^ (x >> 16)) & 0x00000000FFFFFFFFull;
  return (uint32_t)x;
}

// ---------------- key derivation (PARTITIONABLE split) ----------------
__global__ void init_keys(uint32_t* __restrict__ keys /* [256][4] */) {
  int t = threadIdx.x;
  if (t >= TT) return;
  uint32_t kt0, kt1;
  tf2x32(0u, 123u, 0u, (uint32_t)t, kt0, kt1);
  uint32_t a0, a1, b0, b1;
  tf2x32(kt0, kt1, 0u, 0u, a0, a1);  // k1 (hidden)
  tf2x32(kt0, kt1, 0u, 1u, b0, b1);  // k2 (visible)
  keys[4 * t + 0] = a0;
  keys[4 * t + 1] = a1;
  keys[4 * t + 2] = b0;
  keys[4 * t + 3] = b1;
}

// ---------------- W transpose: WT[i][k] = W[k][i] ----------------
__global__ __launch_bounds__(256) void wt_kernel(const float* __restrict__ W,
                                                 float* __restrict__ WT) {
  const int i = blockIdx.x;           // 0..783
  for (int k = threadIdx.x; k < NH; k += 256)
    WT[(size_t)i * NH + k] = W[(size_t)k * NV + i];
}

// ---------------- U transpose+pair: UTP[p][h] = (U[h][2p], U[h][2p+1]) ----------------
__global__ __launch_bounds__(512) void ut_kernel(const float* __restrict__ U,
                                                 float2* __restrict__ UTP) {
  const int p = blockIdx.x;           // 0..249
  const int h = threadIdx.x;          // 0..511
  float2 w;
  if (h < NH) {
    w.x = U[(size_t)h * NH + 2 * p];
    w.y = U[(size_t)h * NH + 2 * p + 1];
  } else {
    w.x = 0.0f; w.y = 0.0f;
  }
  UTP[(size_t)p * 512 + h] = w;
}

// ---------------- Phase A: WV2[bg][t][h][2] = (W @ v_t)[h][b] ----------------
// fmaf(w, x, s) == s + w*x bit-exactly because x in {0,1} (w*x exact).
#define HT_A 20   // 500/20 = 25 h-tiles per t; grid 25*256 = 6400
__global__ __launch_bounds__(256, 4) void wv_gemm(
    const float* __restrict__ v, const float* __restrict__ W,
    float* __restrict__ wv2) {
#pragma clang fp contract(off)
  const int b = threadIdx.x;
  const int bid = (int)blockIdx.x;      // 0..6399
  const int xcd = bid & 7;
  const int slot = bid >> 3;            // 0..799
  const int t = (slot / 25) * 8 + xcd;  // same-t blocks land on one XCD
  const int h0 = (slot % 25) * HT_A;
  const float* vcol = v + (size_t)t * BB + b;   // element k: vcol[k * TT*BB]

  float acc[HT_A];
#pragma unroll
  for (int r = 0; r < HT_A; ++r) acc[r] = 0.0f;

  const int pb[4] = {0, 288, 576, 784};   // kc=288 panels
#pragma unroll 1
  for (int p = 0; p < 3; ++p) {
    float ps[HT_A];
#pragma unroll
    for (int r = 0; r < HT_A; ++r) ps[r] = 0.0f;
    const int k0 = pb[p], k1 = pb[p + 1];
#pragma unroll 8
    for (int k = k0; k < k1; ++k) {
      float x = vcol[(size_t)k * (TT * BB)];
#pragma unroll
      for (int r = 0; r < HT_A; ++r)
        ps[r] = __builtin_fmaf(W[(size_t)(h0 + r) * NV + k], x, ps[r]);
    }
#pragma unroll
    for (int r = 0; r < HT_A; ++r) acc[r] = acc[r] + ps[r];
  }

  // LDS transpose (padded)
  __shared__ float al[HT_A][BB + 1];
#pragma unroll
  for (int r = 0; r < HT_A; ++r) al[r][b] = acc[r];
  __syncthreads();

  // write 40-float runs: wv2[bg][t][h0*2 .. h0*2+39]
  const int sub = b / 40;         // 0..5 (6 bg per iter), b<240 active
  const int idx = b % 40;         // h = h0 + idx/2, j = idx&1
#pragma unroll 1
  for (int it = 0; it < 22; ++it) {
    const int bg = it * 6 + sub;
    if (b < 240 && bg < NBG) {
      wv2[((size_t)bg * TT + t) * 1024 + h0 * 2 + idx] =
          al[idx >> 1][2 * bg + (idx & 1)];
    }
  }
}

// ---------------- Phase B dot: software-pipelined panel dot ----------------
// Strict ascending k (k = 2p then 2p+1), mul-then-add (no FMA: r arbitrary).
template <int PBASE, int NPAIR>
__device__ __forceinline__ f2v dot_panel(const float2* __restrict__ UTPh,
                                         const float4* __restrict__ rof4) {
#pragma clang fp contract(off)
  constexpr int CH = 8;
  constexpr int NC = NPAIR / CH;
  constexpr int REM = NPAIR - NC * CH;
  float2 bufA[CH], bufB[CH];
  f2v acc; acc.x = 0.0f; acc.y = 0.0f;
#pragma unroll
  for (int i = 0; i < CH; ++i) bufA[i] = UTPh[(size_t)(PBASE + i) * 512];
#pragma unroll 1
  for (int c = 0; c < NC; ++c) {
    const int pb = PBASE + c * CH;
    if (c + 1 < NC) {
#pragma unroll
      for (int i = 0; i < CH; ++i)
        bufB[i] = UTPh[(size_t)(pb + CH + i) * 512];
    } else if (REM > 0) {
#pragma unroll
      for (int i = 0; i < REM; ++i)
        bufB[i] = UTPh[(size_t)(pb + CH + i) * 512];
    }
#pragma unroll
    for (int i = 0; i < CH; ++i) {
      const float4 r4 = rof4[pb + i];
      f2v ux; ux.x = bufA[i].x; ux.y = bufA[i].x;
      f2v uy; uy.x = bufA[i].y; uy.y = bufA[i].y;
      f2v r0; r0.x = r4.x; r0.y = r4.y;
      f2v r1; r1.x = r4.z; r1.y = r4.w;
      acc = acc + ux * r0;    // k = 2p
      acc = acc + uy * r1;    // k = 2p+1
    }
#pragma unroll
    for (int i = 0; i < CH; ++i) bufA[i] = bufB[i];
  }
#pragma unroll
  for (int i = 0; i < REM; ++i) {
    const int p = PBASE + NC * CH + i;
    const float4 r4 = rof4[p];
    f2v ux; ux.x = bufA[i].x; ux.y = bufA[i].x;
    f2v uy; uy.x = bufA[i].y; uy.y = bufA[i].y;
    f2v r0; r0.x = r4.x; r0.y = r4.y;
    f2v r1; r1.x = r4.z; r1.y = r4.w;
    acc = acc + ux * r0;
    acc = acc + uy * r1;
  }
  return acc;
}

// ---------------- Phase B: quad-split recurrence ---------------------------
// 256 blocks: bid = q*64 + cg (q = h-quarter 0..3, cg = col-group 0..63).
// All 4 quarters of a cg share bid%8 (same XCD residue under round-robin).
// 512 threads: pan = tid>>8 (Eigen k-panel), idx = tid&255, cp = idx&1
// (b-pair: bg = 2cg+cp), hl = idx>>1 (h = q*128+hl). Adjacent lanes share
// (pan,hl) and differ in cp -> U loads broadcast-merge (halved L2 traffic).
__global__ __launch_bounds__(512) void hidden_quad(
    const float2* __restrict__ UTP, const float* __restrict__ b_h,
    const float* __restrict__ b_init, const uint32_t* __restrict__ keys,
    const float* __restrict__ wv2, uint32_t* __restrict__ hbw,
    unsigned long long* __restrict__ exch, uint32_t* __restrict__ prog) {
#pragma clang fp contract(off)
  const int tid = threadIdx.x;
  const int pan = tid >> 8;           // wave-uniform
  const int idx = tid & 255;
  const int cp = idx & 1;
  const int hl = idx >> 1;            // 0..127
  const int bid = (int)blockIdx.x;
  const int cg = bid & 63;
  const int q = bid >> 6;
  const int h = q * 128 + hl;
  const int hs = (h < NH) ? h : 0;
  const int bg = 2 * cg + cp;
  const int b0 = 2 * bg;              // = 4cg + 2cp

  __shared__ __align__(16) f2v rlds[2][512];  // [cp][k] full r, both cols of bg
  __shared__ f2v ps_l[2][128];        // [cp][hl] panel-1 partials
  __shared__ f2v u_l[2][128];         // [cp][hl] uniforms
  __shared__ uint32_t keyl[2 * TT];

  keyl[tid] = keys[4 * (tid >> 1) + (tid & 1)];
  if (pan == 0) {                     // zero both cp slices: r_lag(0) = 0
    f2v z; z.x = 0.0f; z.y = 0.0f;
    rlds[0][idx] = z; rlds[0][256 + idx] = z;
    rlds[1][idx] = z; rlds[1][256 + idx] = z;
  }
  const float bh = b_h[hs], bi = b_init[hs];
  const float2* __restrict__ UTPh = UTP + h;
  // partner bids (other quarters, same cg)
  const int p1 = (((q + 1) & 3) << 6) | cg;
  const int p2 = (((q + 2) & 3) << 6) | cg;
  const int p3 = (((q + 3) & 3) << 6) | cg;
  __syncthreads();

#pragma unroll 1
  for (int t = 0; t < TT; ++t) {
    const float4* __restrict__ rof4 = (const float4*)&rlds[cp][0];

    f2v wvp; wvp.x = 0.0f; wvp.y = 0.0f;
    f2v a;
    if (pan == 0) {
      wvp = *(const f2v*)&wv2[((size_t)bg * TT + t) * 1024 + h * 2];
      a = dot_panel<0, 144>(UTPh, rof4);      // k = 0..287
    } else {
      a = dot_panel<144, 106>(UTPh, rof4);    // k = 288..499
      ps_l[cp][hl] = a;
      const uint32_t k0 = keyl[2 * t], k1 = keyl[2 * t + 1];
      f2v u;
      u.x = jax_uniform(draw_bits(k0, k1, (uint32_t)(h * BB + b0)));
      u.y = jax_uniform(draw_bits(k0, k1, (uint32_t)(h * BB + b0 + 1)));
      u_l[cp][hl] = u;
    }
    __syncthreads();

    if (pan == 0) {
      const f2v ps = ps_l[cp][hl];
      const float acc0 = a.x + ps.x;          // == (0+panel0)+panel1
      const float acc1 = a.y + ps.y;
      const float bias = (t == 0) ? bi : bh;
      const float pre0 = (wvp.x + acc0) + bias;   // reference order
      const float pre1 = (wvp.y + acc1) + bias;
      const float pp0 = xla_sigmoid(pre0);
      const float pp1 = xla_sigmoid(pre1);
      f2v pv; pv.x = pp0; pv.y = pp1;
      rlds[cp][h] = pv;                       // own quarter update
      if (t != TT - 1) {
        // outbox: relaxed agent atomic -> coherence point, no fences
        __hip_atomic_store(&exch[((size_t)bid * 2 + (t & 1)) * 256 + idx],
                           __builtin_bit_cast(unsigned long long, pv),
                           __ATOMIC_RELAXED, __HIP_MEMORY_SCOPE_AGENT);
      }
      const f2v u = u_l[cp][hl];
      const bool hm0 = u.x < pp0;
      const bool hm1 = u.y < pp1;
      // lane-interleaved masks: even bits = cp0, odd = cp1
      const unsigned long long m0 = __ballot(hm0);
      const unsigned long long m1 = __ballot(hm1);
      const uint32_t e0 = extract_even(m0);        // (bg=2cg,   col 0)
      const uint32_t o0 = extract_even(m0 >> 1);   // (bg=2cg+1, col 0)
      const uint32_t e1 = extract_even(m1);        // (bg=2cg,   col 1)
      const uint32_t o1 = extract_even(m1 >> 1);   // (bg=2cg+1, col 1)
      if ((tid & 63) == 0) {
        uint4 w4; w4.x = e0; w4.y = e1; w4.z = o0; w4.w = o1;
        *(uint4*)&hbw[(size_t)(h >> 5) * (TT * BB) + (size_t)t * BB + 4 * cg] = w4;
      }
    }
    if (t == TT - 1) break;

    // barrier drains outbox atomics (vmcnt) + rlds own-quarter writes
    __syncthreads();
    if (tid == 0)
      __hip_atomic_store(&prog[bid * 32], (uint32_t)(t + 1),
                         __ATOMIC_RELAXED, __HIP_MEMORY_SCOPE_AGENT);
    if (pan == 1) {
      // wait all 3 partners, then pull their quarters (atomics bypass L1)
      const uint32_t tgt = (uint32_t)(t + 1);
      while (__hip_atomic_load(&prog[p1 * 32], __ATOMIC_RELAXED,
                               __HIP_MEMORY_SCOPE_AGENT) < tgt ||
             __hip_atomic_load(&prog[p2 * 32], __ATOMIC_RELAXED,
                               __HIP_MEMORY_SCOPE_AGENT) < tgt ||
             __hip_atomic_load(&prog[p3 * 32], __ATOMIC_RELAXED,
                               __HIP_MEMORY_SCOPE_AGENT) < tgt)
        __builtin_amdgcn_s_sleep(4);
      const int par[3] = {p1, p2, p3};
#pragma unroll
      for (int i = 0; i < 3; ++i) {
        const int pq = (q + 1 + i) & 3;
        unsigned long long w = __hip_atomic_load(
            &exch[((size_t)par[i] * 2 + (t & 1)) * 256 + idx],
            __ATOMIC_RELAXED, __HIP_MEMORY_SCOPE_AGENT);
        rlds[cp][pq * 128 + hl] = __builtin_bit_cast(f2v, w);
      }
    }
    __syncthreads();
  }
}

// ---------------- Phase E: expand packed h bits -> out_r floats ----------------
__global__ __launch_bounds__(256) void expand_r(
    const uint32_t* __restrict__ hbw, float* __restrict__ out_r) {
  const int h = blockIdx.x;           // 0..499
  const int b = threadIdx.x;
  const uint32_t sh = (uint32_t)(h & 31);
  const uint32_t* src = hbw + (size_t)(h >> 5) * (TT * BB);
  float* dst = out_r + (size_t)h * (TT * BB);
#pragma unroll 4
  for (int t = 0; t < TT; ++t) {
    uint32_t w = src[t * BB + b];
    dst[t * BB + b] = (float)((w >> sh) & 1u);
  }
}

// ---------------- Phase C: all visible steps; h read from out_r ----------------
// fmaf(w, h, s) == s + w*h bit-exactly because h in {0,1}.
#define IT_C 16   // 784/16 = 49 i-tiles; grid 49*256 = 12544
__global__ __launch_bounds__(256, 4) void visible_big(
    const float* __restrict__ WT, const float* __restrict__ b_v,
    const uint32_t* __restrict__ keys, const float* __restrict__ hplane,
    float* __restrict__ out_v) {
#pragma clang fp contract(off)
  const int b = threadIdx.x;
  const int bid = (int)blockIdx.x;      // 0..12543
  const int xcd = bid & 7;
  const int slot = bid >> 3;            // 0..1567
  const int t = (slot / 49) * 8 + xcd;  // same-t blocks land on one XCD
  const int i0 = (slot % 49) * IT_C;
  const float* hcol = hplane + (size_t)t * BB + b;  // element k: hcol[k * TT*BB]

  float acc[IT_C];
#pragma unroll
  for (int r = 0; r < IT_C; ++r) acc[r] = 0.0f;

  const int pb[3] = {0, 288, 500};
#pragma unroll 1
  for (int p = 0; p < 2; ++p) {
    float ps[IT_C];
#pragma unroll
    for (int r = 0; r < IT_C; ++r) ps[r] = 0.0f;
    const int k0 = pb[p], k1 = pb[p + 1];
#pragma unroll 8
    for (int k = k0; k < k1; ++k) {
      float hh = hcol[(size_t)k * (TT * BB)];
#pragma unroll
      for (int r = 0; r < IT_C; ++r)
        ps[r] = __builtin_fmaf(WT[(size_t)(i0 + r) * NH + k], hh, ps[r]);
    }
#pragma unroll
    for (int r = 0; r < IT_C; ++r) acc[r] = acc[r] + ps[r];
  }

  const uint32_t key0 = keys[4 * t + 2], key1 = keys[4 * t + 3];
#pragma unroll
  for (int r = 0; r < IT_C; ++r) {
    const int i = i0 + r;
    float pre = acc[r] + b_v[i];
    float p = xla_sigmoid(pre);
    uint32_t j = (uint32_t)(i * BB + b);
    float u = jax_uniform(draw_bits(key0, key1, j));
    out_v[(size_t)i * (TT * BB) + (size_t)t * BB + b] = (u < p) ? 1.0f : 0.0f;
  }
}

extern "C" void kernel_launch(void* const* d_in, const int* in_sizes, int n_in,
                              void* d_out, int out_size, void* d_ws, size_t ws_size,
                              hipStream_t stream) {
  const float* v      = (const float*)d_in[0];
  const float* W      = (const float*)d_in[1];
  const float* U      = (const float*)d_in[2];
  const float* b_h    = (const float*)d_in[3];
  const float* b_v    = (const float*)d_in[4];
  const float* b_init = (const float*)d_in[5];

  float* out_v = (float*)d_out;                       // (784,256,256) = 205.5 MB
  float* out_r = out_v + (size_t)NV * TT * BB;        // (500,256,256) = 131 MB

  // Staging inside the out_v region (dead before phase C overwrites out_v):
  //   wv2:  134.2 MB at offset 0
  //   exch: 256 blocks x 2 slots x 256 u64 = 1 MB after wv2
  //   prog: 256 x 32 u32 (128B-spaced) after exch
  // UTP (1 MB) at head of out_r region (dead before phase E overwrites out_r).
  float* wv2 = out_v;
  unsigned long long* exch =
      (unsigned long long*)(out_v + (size_t)NBG * TT * 1024);
  uint32_t* prog = (uint32_t*)(exch + (size_t)256 * 2 * 256);
  float2* UTP = (float2*)out_r;

  // ws: WT (1.57 MB) + keys (4 KB) + hbw (4.19 MB)
  float* WT = (float*)d_ws;
  uint32_t* keys = (uint32_t*)(WT + (size_t)NV * NH);
  uint32_t* hbw = keys + TT * 4;   // [16][256][256] u32

  hipMemsetAsync(prog, 0, 256 * 32 * sizeof(uint32_t), stream);
  init_keys<<<1, 256, 0, stream>>>(keys);
  wt_kernel<<<NV, 256, 0, stream>>>(W, WT);
  ut_kernel<<<250, 512, 0, stream>>>(U, UTP);

  wv_gemm<<<25 * TT, 256, 0, stream>>>(v, W, wv2);

  hidden_quad<<<256, 512, 0, stream>>>(UTP, b_h, b_init, keys, wv2, hbw,
                                       exch, prog);

  expand_r<<<NH, 256, 0, stream>>>(hbw, out_r);

  visible_big<<<49 * TT, 256, 0, stream>>>(WT, b_v, keys, out_r, out_v);
}

// Round 14
// 4852.431 us; speedup vs baseline: 1.0009x; 1.0009x over previous
//
#include <hip/hip_runtime.h>
#include <stdint.h>

// RTRBM CD-1: bit-exact replication of the JAX-CPU reference.
// Phase A: wv_gemm — XCD-swizzled, HT_A=20, launch_bounds(256,4) (r12).
// Phase B: hidden_quad — block = (col-group cg of 4 cols, h-quarter q of 128).
//          Lanes interleave the 2 b-pair workers (cp) -> U loads broadcast-merge.
//          r stored PAIR-INTERLEAVED in LDS: rq[pair][cp] float4 -> the lane
//          pair (cp=0/1) reads 16B-apart addresses = different banks = zero
//          conflicts (r13's [cp][k] layout was 4KB apart = same bank, 2.7e8
//          conflicts). 3-partner relaxed-atomic r exchange (r11 recipe).
// Phase E: expand bits -> out_r floats.
// Phase C: visible_big — spill fix + XCD swizzle (r12).
// Sizes: V=784, H=500, T=256, B=256. RNG: threefry partitionable.
// Eigen MT blocking (AVX no-FMA jaxlib): kc=288. K=784 -> [288,288,208]; K=500 -> [288,212].
#define NV 784
#define NH 500
#define TT 256
#define BB 256
#define NBG 128   // b-pairs

typedef float f2v __attribute__((ext_vector_type(2)));

// ---------------- threefry2x32 (JAX PRNG), exact ----------------
__device__ __forceinline__ void tf2x32(uint32_t ks0, uint32_t ks1,
                                       uint32_t x0, uint32_t x1,
                                       uint32_t& y0, uint32_t& y1) {
  uint32_t ks2 = ks0 ^ ks1 ^ 0x1BD11BDAu;
  x0 += ks0; x1 += ks1;
#define TFROT(r) { x0 += x1; x1 = (x1 << (r)) | (x1 >> (32 - (r))); x1 ^= x0; }
  TFROT(13) TFROT(15) TFROT(26) TFROT(6)
  x0 += ks1; x1 += ks2 + 1u;
  TFROT(17) TFROT(29) TFROT(16) TFROT(24)
  x0 += ks2; x1 += ks0 + 2u;
  TFROT(13) TFROT(15) TFROT(26) TFROT(6)
  x0 += ks0; x1 += ks1 + 3u;
  TFROT(17) TFROT(29) TFROT(16) TFROT(24)
  x0 += ks1; x1 += ks2 + 4u;
  TFROT(13) TFROT(15) TFROT(26) TFROT(6)
  x0 += ks2; x1 += ks0 + 5u;
#undef TFROT
  y0 = x0; y1 = x1;
}

__device__ __forceinline__ float jax_uniform(uint32_t bits) {
#pragma clang fp contract(off)
  float f = __uint_as_float((bits >> 9) | 0x3F800000u);
  return f - 1.0f;
}

// PARTITIONABLE random_bits, 32-bit: bits[j] = y0 ^ y1 of threefry(key; 0, j)
__device__ __forceinline__ uint32_t draw_bits(uint32_t k0, uint32_t k1,
                                              uint32_t j) {
  uint32_t y0, y1;
  tf2x32(k0, k1, 0u, j, y0, y1);
  return y0 ^ y1;
}

// ---------------- XLA CPU exp (Cephes/Eigen poly, no FMA) ----------------
__device__ __forceinline__ float xla_expf(float x) {
#pragma clang fp contract(off)
  float xc = fminf(fmaxf(x, -88.3762626647949f), 88.3762626647950f);
  float fx = floorf(xc * 1.44269504088896341f + 0.5f);
  float tmp = 0.693359375f * fx;
  float z = -2.12194440e-4f * fx;
  float xr = xc - tmp;
  xr = xr - z;
  z = xr * xr;
  float y = xr * 1.9875691500e-4f + 1.3981999507e-3f;
  y = y * xr + 8.3334519073e-3f;
  y = y * xr + 4.1665795894e-2f;
  y = y * xr + 1.6666665459e-1f;
  y = y * xr + 5.0000001201e-1f;
  y = y * z + xr;
  y = 1.0f + y;
  int e = (int)fx;
  float pow2 = __int_as_float((uint32_t)(e + 127) << 23);
  return y * pow2;
}

__device__ __forceinline__ float xla_sigmoid(float x) {
#pragma clang fp contract(off)
  float e = xla_expf(-x);
  float d = 1.0f + e;
  return 1.0f / d;
}

// even-bit compress: 64-bit mask -> 32 bits taken from even lane positions
__device__ __forceinline__ uint32_t extract_even(unsigned long long x) {
  x &= 0x5555555555555555ull;
  x = (x ^ (x >> 1)) & 0x3333333333333333ull;
  x = (x ^ (x >> 2)) & 0x0F0F0F0F0F0F0F0Full;
  x = (x ^ (x >> 4)) & 0x00FF00FF00FF00FFull;
  x = (x ^ (x >> 8)) & 0x0000FFFF0000FFFFull;
  x = (x ^ (x >> 16)) & 0x00000000FFFFFFFFull;
  return (uint32_t)x;
}

// ---------------- key derivation (PARTITIONABLE split) ----------------
__global__ void init_keys(uint32_t* __restrict__ keys /* [256][4] */) {
  int t = threadIdx.x;
  if (t >= TT) return;
  uint32_t kt0, kt1;
  tf2x32(0u, 123u, 0u, (uint32_t)t, kt0, kt1);
  uint32_t a0, a1, b0, b1;
  tf2x32(kt0, kt1, 0u, 0u, a0, a1);  // k1 (hidden)
  tf2x32(kt0, kt1, 0u, 1u, b0, b1);  // k2 (visible)
  keys[4 * t + 0] = a0;
  keys[4 * t + 1] = a1;
  keys[4 * t + 2] = b0;
  keys[4 * t + 3] = b1;
}

// ---------------- W transpose: WT[i][k] = W[k][i] ----------------
__global__ __launch_bounds__(256) void wt_kernel(const float* __restrict__ W,
                                                 float* __restrict__ WT) {
  const int i = blockIdx.x;           // 0..783
  for (int k = threadIdx.x; k < NH; k += 256)
    WT[(size_t)i * NH + k] = W[(size_t)k * NV + i];
}

// ---------------- U transpose+pair: UTP[p][h] = (U[h][2p], U[h][2p+1]) ----------------
__global__ __launch_bounds__(512) void ut_kernel(const float* __restrict__ U,
                                                 float2* __restrict__ UTP) {
  const int p = blockIdx.x;           // 0..249
  const int h = threadIdx.x;          // 0..511
  float2 w;
  if (h < NH) {
    w.x = U[(size_t)h * NH + 2 * p];
    w.y = U[(size_t)h * NH + 2 * p + 1];
  } else {
    w.x = 0.0f; w.y = 0.0f;
  }
  UTP[(size_t)p * 512 + h] = w;
}

// ---------------- Phase A: WV2[bg][t][h][2] = (W @ v_t)[h][b] ----------------
// fmaf(w, x, s) == s + w*x bit-exactly because x in {0,1} (w*x exact).
#define HT_A 20   // 500/20 = 25 h-tiles per t; grid 25*256 = 6400
__global__ __launch_bounds__(256, 4) void wv_gemm(
    const float* __restrict__ v, const float* __restrict__ W,
    float* __restrict__ wv2) {
#pragma clang fp contract(off)
  const int b = threadIdx.x;
  const int bid = (int)blockIdx.x;      // 0..6399
  const int xcd = bid & 7;
  const int slot = bid >> 3;            // 0..799
  const int t = (slot / 25) * 8 + xcd;  // same-t blocks land on one XCD
  const int h0 = (slot % 25) * HT_A;
  const float* vcol = v + (size_t)t * BB + b;   // element k: vcol[k * TT*BB]

  float acc[HT_A];
#pragma unroll
  for (int r = 0; r < HT_A; ++r) acc[r] = 0.0f;

  const int pb[4] = {0, 288, 576, 784};   // kc=288 panels
#pragma unroll 1
  for (int p = 0; p < 3; ++p) {
    float ps[HT_A];
#pragma unroll
    for (int r = 0; r < HT_A; ++r) ps[r] = 0.0f;
    const int k0 = pb[p], k1 = pb[p + 1];
#pragma unroll 8
    for (int k = k0; k < k1; ++k) {
      float x = vcol[(size_t)k * (TT * BB)];
#pragma unroll
      for (int r = 0; r < HT_A; ++r)
        ps[r] = __builtin_fmaf(W[(size_t)(h0 + r) * NV + k], x, ps[r]);
    }
#pragma unroll
    for (int r = 0; r < HT_A; ++r) acc[r] = acc[r] + ps[r];
  }

  // LDS transpose (padded)
  __shared__ float al[HT_A][BB + 1];
#pragma unroll
  for (int r = 0; r < HT_A; ++r) al[r][b] = acc[r];
  __syncthreads();

  // write 40-float runs: wv2[bg][t][h0*2 .. h0*2+39]
  const int sub = b / 40;         // 0..5 (6 bg per iter), b<240 active
  const int idx = b % 40;         // h = h0 + idx/2, j = idx&1
#pragma unroll 1
  for (int it = 0; it < 22; ++it) {
    const int bg = it * 6 + sub;
    if (b < 240 && bg < NBG) {
      wv2[((size_t)bg * TT + t) * 1024 + h0 * 2 + idx] =
          al[idx >> 1][2 * bg + (idx & 1)];
    }
  }
}

// ---------------- Phase B dot: software-pipelined panel dot ----------------
// Strict ascending k (k = 2p then 2p+1), mul-then-add (no FMA: r arbitrary).
// rq layout: float4 rq[p*2 + cp] = (r[2p].c0, r[2p].c1, r[2p+1].c0, r[2p+1].c1)
// for slice cp -> lane pair (cp=0/1) reads 16B apart = different banks.
template <int PBASE, int NPAIR>
__device__ __forceinline__ f2v dot_panel(const float2* __restrict__ UTPh,
                                         const float4* __restrict__ rq_cp) {
#pragma clang fp contract(off)
  constexpr int CH = 8;
  constexpr int NC = NPAIR / CH;
  constexpr int REM = NPAIR - NC * CH;
  float2 bufA[CH], bufB[CH];
  f2v acc; acc.x = 0.0f; acc.y = 0.0f;
#pragma unroll
  for (int i = 0; i < CH; ++i) bufA[i] = UTPh[(size_t)(PBASE + i) * 512];
#pragma unroll 1
  for (int c = 0; c < NC; ++c) {
    const int pb = PBASE + c * CH;
    if (c + 1 < NC) {
#pragma unroll
      for (int i = 0; i < CH; ++i)
        bufB[i] = UTPh[(size_t)(pb + CH + i) * 512];
    } else if (REM > 0) {
#pragma unroll
      for (int i = 0; i < REM; ++i)
        bufB[i] = UTPh[(size_t)(pb + CH + i) * 512];
    }
#pragma unroll
    for (int i = 0; i < CH; ++i) {
      const float4 r4 = rq_cp[2 * (pb + i)];   // pair-interleaved, stride 2
      f2v ux; ux.x = bufA[i].x; ux.y = bufA[i].x;
      f2v uy; uy.x = bufA[i].y; uy.y = bufA[i].y;
      f2v r0; r0.x = r4.x; r0.y = r4.y;
      f2v r1; r1.x = r4.z; r1.y = r4.w;
      acc = acc + ux * r0;    // k = 2p
      acc = acc + uy * r1;    // k = 2p+1
    }
#pragma unroll
    for (int i = 0; i < CH; ++i) bufA[i] = bufB[i];
  }
#pragma unroll
  for (int i = 0; i < REM; ++i) {
    const int p = PBASE + NC * CH + i;
    const float4 r4 = rq_cp[2 * p];
    f2v ux; ux.x = bufA[i].x; ux.y = bufA[i].x;
    f2v uy; uy.x = bufA[i].y; uy.y = bufA[i].y;
    f2v r0; r0.x = r4.x; r0.y = r4.y;
    f2v r1; r1.x = r4.z; r1.y = r4.w;
    acc = acc + ux * r0;
    acc = acc + uy * r1;
  }
  return acc;
}

// ---------------- Phase B: quad-split recurrence ---------------------------
// 256 blocks: bid = q*64 + cg (q = h-quarter 0..3, cg = col-group 0..63).
// 512 threads: pan = tid>>8, idx = tid&255, cp = idx&1 (bg = 2cg+cp),
// hl = idx>>1 (h = q*128+hl). Adjacent lanes share (pan,hl), differ in cp ->
// U loads broadcast-merge; r reads hit 2 distinct banks (no conflicts).
__global__ __launch_bounds__(512) void hidden_quad(
    const float2* __restrict__ UTP, const float* __restrict__ b_h,
    const float* __restrict__ b_init, const uint32_t* __restrict__ keys,
    const float* __restrict__ wv2, uint32_t* __restrict__ hbw,
    unsigned long long* __restrict__ exch, uint32_t* __restrict__ prog) {
#pragma clang fp contract(off)
  const int tid = threadIdx.x;
  const int pan = tid >> 8;           // wave-uniform
  const int idx = tid & 255;
  const int cp = idx & 1;
  const int hl = idx >> 1;            // 0..127
  const int bid = (int)blockIdx.x;
  const int cg = bid & 63;
  const int q = bid >> 6;
  const int h = q * 128 + hl;
  const int hs = (h < NH) ? h : 0;
  const int bg = 2 * cg + cp;
  const int b0 = 2 * bg;              // = 4cg + 2cp

  __shared__ __align__(16) float4 rq[512];    // [pair p][cp], 250*2 used
  __shared__ f2v ps_l[256];           // [hl][cp] panel-1 partials
  __shared__ f2v u_l[256];            // [hl][cp] uniforms
  __shared__ uint32_t keyl[2 * TT];

  keyl[tid] = keys[4 * (tid >> 1) + (tid & 1)];
  if (pan == 0) {                     // zero both halves once (r_lag(0) = 0)
    float4 z; z.x = 0.0f; z.y = 0.0f; z.z = 0.0f; z.w = 0.0f;
    rq[idx] = z; rq[256 + idx] = z;
  }
  const float bh = b_h[hs], bi = b_init[hs];
  const float2* __restrict__ UTPh = UTP + h;
  f2v* __restrict__ rw = (f2v*)rq;    // f2v view: index (h>>1)*4 + cp*2 + (h&1)
  const float4* __restrict__ rq_cp = rq + cp;
  // partner bids (other quarters, same cg -> same XCD residue mod 8)
  const int p1 = (((q + 1) & 3) << 6) | cg;
  const int p2 = (((q + 2) & 3) << 6) | cg;
  const int p3 = (((q + 3) & 3) << 6) | cg;
  __syncthreads();

#pragma unroll 1
  for (int t = 0; t < TT; ++t) {
    f2v wvp; wvp.x = 0.0f; wvp.y = 0.0f;
    f2v a;
    if (pan == 0) {
      wvp = *(const f2v*)&wv2[((size_t)bg * TT + t) * 1024 + h * 2];
      a = dot_panel<0, 144>(UTPh, rq_cp);     // k = 0..287
    } else {
      a = dot_panel<144, 106>(UTPh, rq_cp);   // k = 288..499
      ps_l[hl * 2 + cp] = a;
      const uint32_t k0 = keyl[2 * t], k1 = keyl[2 * t + 1];
      f2v u;
      u.x = jax_uniform(draw_bits(k0, k1, (uint32_t)(h * BB + b0)));
      u.y = jax_uniform(draw_bits(k0, k1, (uint32_t)(h * BB + b0 + 1)));
      u_l[hl * 2 + cp] = u;
    }
    __syncthreads();

    if (pan == 0) {
      const f2v ps = ps_l[hl * 2 + cp];
      const float acc0 = a.x + ps.x;          // == (0+panel0)+panel1
      const float acc1 = a.y + ps.y;
      const float bias = (t == 0) ? bi : bh;
      const float pre0 = (wvp.x + acc0) + bias;   // reference order
      const float pre1 = (wvp.y + acc1) + bias;
      const float pp0 = xla_sigmoid(pre0);
      const float pp1 = xla_sigmoid(pre1);
      f2v pv; pv.x = pp0; pv.y = pp1;
      rw[(h >> 1) * 4 + cp * 2 + (h & 1)] = pv;   // own quarter, pair-interleaved
      if (t != TT - 1) {
        __hip_atomic_store(&exch[((size_t)bid * 2 + (t & 1)) * 256 + idx],
                           __builtin_bit_cast(unsigned long long, pv),
                           __ATOMIC_RELAXED, __HIP_MEMORY_SCOPE_AGENT);
      }
      const f2v u = u_l[hl * 2 + cp];
      const bool hm0 = u.x < pp0;
      const bool hm1 = u.y < pp1;
      // lane-interleaved masks: even bits = cp0, odd = cp1
      const unsigned long long m0 = __ballot(hm0);
      const unsigned long long m1 = __ballot(hm1);
      const uint32_t e0 = extract_even(m0);        // (bg=2cg,   col 0)
      const uint32_t o0 = extract_even(m0 >> 1);   // (bg=2cg+1, col 0)
      const uint32_t e1 = extract_even(m1);        // (bg=2cg,   col 1)
      const uint32_t o1 = extract_even(m1 >> 1);   // (bg=2cg+1, col 1)
      if ((tid & 63) == 0) {
        uint4 w4; w4.x = e0; w4.y = e1; w4.z = o0; w4.w = o1;
        *(uint4*)&hbw[(size_t)(h >> 5) * (TT * BB) + (size_t)t * BB + 4 * cg] = w4;
      }
    }
    if (t == TT - 1) break;

    // barrier drains outbox atomics (vmcnt) + rq own-quarter writes
    __syncthreads();
    if (tid == 0)
      __hip_atomic_store(&prog[bid * 32], (uint32_t)(t + 1),
                         __ATOMIC_RELAXED, __HIP_MEMORY_SCOPE_AGENT);
    if (pan == 1) {
      const uint32_t tgt = (uint32_t)(t + 1);
      while (__hip_atomic_load(&prog[p1 * 32], __ATOMIC_RELAXED,
                               __HIP_MEMORY_SCOPE_AGENT) < tgt ||
             __hip_atomic_load(&prog[p2 * 32], __ATOMIC_RELAXED,
                               __HIP_MEMORY_SCOPE_AGENT) < tgt ||
             __hip_atomic_load(&prog[p3 * 32], __ATOMIC_RELAXED,
                               __HIP_MEMORY_SCOPE_AGENT) < tgt)
        __builtin_amdgcn_s_sleep(4);
      const int par[3] = {p1, p2, p3};
#pragma unroll
      for (int i = 0; i < 3; ++i) {
        const int pq = (q + 1 + i) & 3;
        unsigned long long w = __hip_atomic_load(
            &exch[((size_t)par[i] * 2 + (t & 1)) * 256 + idx],
            __ATOMIC_RELAXED, __HIP_MEMORY_SCOPE_AGENT);
        const int hh = pq * 128 + hl;
        rw[(hh >> 1) * 4 + cp * 2 + (hh & 1)] = __builtin_bit_cast(f2v, w);
      }
    }
    __syncthreads();
  }
}

// ---------------- Phase E: expand packed h bits -> out_r floats ----------------
__global__ __launch_bounds__(256) void expand_r(
    const uint32_t* __restrict__ hbw, float* __restrict__ out_r) {
  const int h = blockIdx.x;           // 0..499
  const int b = threadIdx.x;
  const uint32_t sh = (uint32_t)(h & 31);
  const uint32_t* src = hbw + (size_t)(h >> 5) * (TT * BB);
  float* dst = out_r + (size_t)h * (TT * BB);
#pragma unroll 4
  for (int t = 0; t < TT; ++t) {
    uint32_t w = src[t * BB + b];
    dst[t * BB + b] = (float)((w >> sh) & 1u);
  }
}

// ---------------- Phase C: all visible steps; h read from out_r ----------------
// fmaf(w, h, s) == s + w*h bit-exactly because h in {0,1}.
#define IT_C 16   // 784/16 = 49 i-tiles; grid 49*256 = 12544
__global__ __launch_bounds__(256, 4) void visible_big(
    const float* __restrict__ WT, const float* __restrict__ b_v,
    const uint32_t* __restrict__ keys, const float* __restrict__ hplane,
    float* __restrict__ out_v) {
#pragma clang fp contract(off)
  const int b = threadIdx.x;
  const int bid = (int)blockIdx.x;      // 0..12543
  const int xcd = bid & 7;
  const int slot = bid >> 3;            // 0..1567
  const int t = (slot / 49) * 8 + xcd;  // same-t blocks land on one XCD
  const int i0 = (slot % 49) * IT_C;
  const float* hcol = hplane + (size_t)t * BB + b;  // element k: hcol[k * TT*BB]

  float acc[IT_C];
#pragma unroll
  for (int r = 0; r < IT_C; ++r) acc[r] = 0.0f;

  const int pb[3] = {0, 288, 500};
#pragma unroll 1
  for (int p = 0; p < 2; ++p) {
    float ps[IT_C];
#pragma unroll
    for (int r = 0; r < IT_C; ++r) ps[r] = 0.0f;
    const int k0 = pb[p], k1 = pb[p + 1];
#pragma unroll 8
    for (int k = k0; k < k1; ++k) {
      float hh = hcol[(size_t)k * (TT * BB)];
#pragma unroll
      for (int r = 0; r < IT_C; ++r)
        ps[r] = __builtin_fmaf(WT[(size_t)(i0 + r) * NH + k], hh, ps[r]);
    }
#pragma unroll
    for (int r = 0; r < IT_C; ++r) acc[r] = acc[r] + ps[r];
  }

  const uint32_t key0 = keys[4 * t + 2], key1 = keys[4 * t + 3];
#pragma unroll
  for (int r = 0; r < IT_C; ++r) {
    const int i = i0 + r;
    float pre = acc[r] + b_v[i];
    float p = xla_sigmoid(pre);
    uint32_t j = (uint32_t)(i * BB + b);
    float u = jax_uniform(draw_bits(key0, key1, j));
    out_v[(size_t)i * (TT * BB) + (size_t)t * BB + b] = (u < p) ? 1.0f : 0.0f;
  }
}

extern "C" void kernel_launch(void* const* d_in, const int* in_sizes, int n_in,
                              void* d_out, int out_size, void* d_ws, size_t ws_size,
                              hipStream_t stream) {
  const float* v      = (const float*)d_in[0];
  const float* W      = (const float*)d_in[1];
  const float* U      = (const float*)d_in[2];
  const float* b_h    = (const float*)d_in[3];
  const float* b_v    = (const float*)d_in[4];
  const float* b_init = (const float*)d_in[5];

  float* out_v = (float*)d_out;                       // (784,256,256) = 205.5 MB
  float* out_r = out_v + (size_t)NV * TT * BB;        // (500,256,256) = 131 MB

  // Staging inside the out_v region (dead before phase C overwrites out_v):
  //   wv2:  134.2 MB at offset 0
  //   exch: 256 blocks x 2 slots x 256 u64 = 1 MB after wv2
  //   prog: 256 x 32 u32 (128B-spaced) after exch
  // UTP (1 MB) at head of out_r region (dead before phase E overwrites out_r).
  float* wv2 = out_v;
  unsigned long long* exch =
      (unsigned long long*)(out_v + (size_t)NBG * TT * 1024);
  uint32_t* prog = (uint32_t*)(exch + (size_t)256 * 2 * 256);
  float2* UTP = (float2*)out_r;

  // ws: WT (1.57 MB) + keys (4 KB) + hbw (4.19 MB)
  float* WT = (float*)d_ws;
  uint32_t* keys = (uint32_t*)(WT + (size_t)NV * NH);
  uint32_t* hbw = keys + TT * 4;   // [16][256][256] u32

  hipMemsetAsync(prog, 0, 256 * 32 * sizeof(uint32_t), stream);
  init_keys<<<1, 256, 0, stream>>>(keys);
  wt_kernel<<<NV, 256, 0, stream>>>(W, WT);
  ut_kernel<<<250, 512, 0, stream>>>(U, UTP);

  wv_gemm<<<25 * TT, 256, 0, stream>>>(v, W, wv2);

  hidden_quad<<<256, 512, 0, stream>>>(UTP, b_h, b_init, keys, wv2, hbw,
                                       exch, prog);

  expand_r<<<NH, 256, 0, stream>>>(hbw, out_r);

  visible_big<<<49 * TT, 256, 0, stream>>>(WT, b_v, keys, out_r, out_v);
}

// Round 15
// 4502.665 us; speedup vs baseline: 1.0787x; 1.0777x over previous
//
#include <hip/hip_runtime.h>
#include <stdint.h>

// RTRBM CD-1: bit-exact replication of the JAX-CPU reference.
// Phase A: wv_gemm — XCD-swizzled, HT_A=20, launch_bounds(256,4) (r12).
// Phase B: hidden_quad — quad h-split, cp-interleaved lanes, pair-interleaved
//          r in LDS (0 conflicts, r14). NEW (r15): chunk-blocked U layout
//          UTPC[c][h][8] -> per-chunk 64B contiguous = 4x dwordx4 with imm
//          offsets + 1 base add (was 8x dwordx2 + 8 addr calcs). Same
//          summation order; 3-partner relaxed-atomic exchange (r11 recipe).
// Phase E: expand bits -> out_r floats.
// Phase C: visible_big — spill fix + XCD swizzle (r12).
// Sizes: V=784, H=500, T=256, B=256. RNG: threefry partitionable.
// Eigen MT blocking (AVX no-FMA jaxlib): kc=288. K=784 -> [288,288,208]; K=500 -> [288,212].
#define NV 784
#define NH 500
#define TT 256
#define BB 256
#define NBG 128   // b-pairs

typedef float f2v __attribute__((ext_vector_type(2)));

// ---------------- threefry2x32 (JAX PRNG), exact ----------------
__device__ __forceinline__ void tf2x32(uint32_t ks0, uint32_t ks1,
                                       uint32_t x0, uint32_t x1,
                                       uint32_t& y0, uint32_t& y1) {
  uint32_t ks2 = ks0 ^ ks1 ^ 0x1BD11BDAu;
  x0 += ks0; x1 += ks1;
#define TFROT(r) { x0 += x1; x1 = (x1 << (r)) | (x1 >> (32 - (r))); x1 ^= x0; }
  TFROT(13) TFROT(15) TFROT(26) TFROT(6)
  x0 += ks1; x1 += ks2 + 1u;
  TFROT(17) TFROT(29) TFROT(16) TFROT(24)
  x0 += ks2; x1 += ks0 + 2u;
  TFROT(13) TFROT(15) TFROT(26) TFROT(6)
  x0 += ks0; x1 += ks1 + 3u;
  TFROT(17) TFROT(29) TFROT(16) TFROT(24)
  x0 += ks1; x1 += ks2 + 4u;
  TFROT(13) TFROT(15) TFROT(26) TFROT(6)
  x0 += ks2; x1 += ks0 + 5u;
#undef TFROT
  y0 = x0; y1 = x1;
}

__device__ __forceinline__ float jax_uniform(uint32_t bits) {
#pragma clang fp contract(off)
  float f = __uint_as_float((bits >> 9) | 0x3F800000u);
  return f - 1.0f;
}

// PARTITIONABLE random_bits, 32-bit: bits[j] = y0 ^ y1 of threefry(key; 0, j)
__device__ __forceinline__ uint32_t draw_bits(uint32_t k0, uint32_t k1,
                                              uint32_t j) {
  uint32_t y0, y1;
  tf2x32(k0, k1, 0u, j, y0, y1);
  return y0 ^ y1;
}

// ---------------- XLA CPU exp (Cephes/Eigen poly, no FMA) ----------------
__device__ __forceinline__ float xla_expf(float x) {
#pragma clang fp contract(off)
  float xc = fminf(fmaxf(x, -88.3762626647949f), 88.3762626647950f);
  float fx = floorf(xc * 1.44269504088896341f + 0.5f);
  float tmp = 0.693359375f * fx;
  float z = -2.12194440e-4f * fx;
  float xr = xc - tmp;
  xr = xr - z;
  z = xr * xr;
  float y = xr * 1.9875691500e-4f + 1.3981999507e-3f;
  y = y * xr + 8.3334519073e-3f;
  y = y * xr + 4.1665795894e-2f;
  y = y * xr + 1.6666665459e-1f;
  y = y * xr + 5.0000001201e-1f;
  y = y * z + xr;
  y = 1.0f + y;
  int e = (int)fx;
  float pow2 = __int_as_float((uint32_t)(e + 127) << 23);
  return y * pow2;
}

__device__ __forceinline__ float xla_sigmoid(float x) {
#pragma clang fp contract(off)
  float e = xla_expf(-x);
  float d = 1.0f + e;
  return 1.0f / d;
}

// even-bit compress: 64-bit mask -> 32 bits taken from even lane positions
__device__ __forceinline__ uint32_t extract_even(unsigned long long x) {
  x &= 0x5555555555555555ull;
  x = (x ^ (x >> 1)) & 0x3333333333333333ull;
  x = (x ^ (x >> 2)) & 0x0F0F0F0F0F0F0F0Full;
  x = (x ^ (x >> 4)) & 0x00FF00FF00FF00FFull;
  x = (x ^ (x >> 8)) & 0x0000FFFF0000FFFFull;
  x = (x ^ (x >> 16)) & 0x00000000FFFFFFFFull;
  return (uint32_t)x;
}

// ---------------- key derivation (PARTITIONABLE split) ----------------
__global__ void init_keys(uint32_t* __restrict__ keys /* [256][4] */) {
  int t = threadIdx.x;
  if (t >= TT) return;
  uint32_t kt0, kt1;
  tf2x32(0u, 123u, 0u, (uint32_t)t, kt0, kt1);
  uint32_t a0, a1, b0, b1;
  tf2x32(kt0, kt1, 0u, 0u, a0, a1);  // k1 (hidden)
  tf2x32(kt0, kt1, 0u, 1u, b0, b1);  // k2 (visible)
  keys[4 * t + 0] = a0;
  keys[4 * t + 1] = a1;
  keys[4 * t + 2] = b0;
  keys[4 * t + 3] = b1;
}

// ---------------- W transpose: WT[i][k] = W[k][i] ----------------
__global__ __launch_bounds__(256) void wt_kernel(const float* __restrict__ W,
                                                 float* __restrict__ WT) {
  const int i = blockIdx.x;           // 0..783
  for (int k = threadIdx.x; k < NH; k += 256)
    WT[(size_t)i * NH + k] = W[(size_t)k * NV + i];
}

// ---------------- U chunk-blocked transpose ----------------
// UTPC element (c, h, i) at ((c*512 + h)*8 + i) float2 = (U[h][2p], U[h][2p+1]),
// p = 8c+i. Per-thread chunk = 64 contiguous bytes; h-lanes stride 64B.
__global__ __launch_bounds__(512) void ut_kernel(const float* __restrict__ U,
                                                 float2* __restrict__ UTPC) {
  const int p = blockIdx.x;           // 0..249
  const int h = threadIdx.x;          // 0..511
  float2 w;
  if (h < NH) {
    w.x = U[(size_t)h * NH + 2 * p];
    w.y = U[(size_t)h * NH + 2 * p + 1];
  } else {
    w.x = 0.0f; w.y = 0.0f;
  }
  UTPC[((size_t)(p >> 3) * 512 + h) * 8 + (p & 7)] = w;
}

// ---------------- Phase A: WV2[bg][t][h][2] = (W @ v_t)[h][b] ----------------
// fmaf(w, x, s) == s + w*x bit-exactly because x in {0,1} (w*x exact).
#define HT_A 20   // 500/20 = 25 h-tiles per t; grid 25*256 = 6400
__global__ __launch_bounds__(256, 4) void wv_gemm(
    const float* __restrict__ v, const float* __restrict__ W,
    float* __restrict__ wv2) {
#pragma clang fp contract(off)
  const int b = threadIdx.x;
  const int bid = (int)blockIdx.x;      // 0..6399
  const int xcd = bid & 7;
  const int slot = bid >> 3;            // 0..799
  const int t = (slot / 25) * 8 + xcd;  // same-t blocks land on one XCD
  const int h0 = (slot % 25) * HT_A;
  const float* vcol = v + (size_t)t * BB + b;   // element k: vcol[k * TT*BB]

  float acc[HT_A];
#pragma unroll
  for (int r = 0; r < HT_A; ++r) acc[r] = 0.0f;

  const int pb[4] = {0, 288, 576, 784};   // kc=288 panels
#pragma unroll 1
  for (int p = 0; p < 3; ++p) {
    float ps[HT_A];
#pragma unroll
    for (int r = 0; r < HT_A; ++r) ps[r] = 0.0f;
    const int k0 = pb[p], k1 = pb[p + 1];
#pragma unroll 8
    for (int k = k0; k < k1; ++k) {
      float x = vcol[(size_t)k * (TT * BB)];
#pragma unroll
      for (int r = 0; r < HT_A; ++r)
        ps[r] = __builtin_fmaf(W[(size_t)(h0 + r) * NV + k], x, ps[r]);
    }
#pragma unroll
    for (int r = 0; r < HT_A; ++r) acc[r] = acc[r] + ps[r];
  }

  // LDS transpose (padded)
  __shared__ float al[HT_A][BB + 1];
#pragma unroll
  for (int r = 0; r < HT_A; ++r) al[r][b] = acc[r];
  __syncthreads();

  // write 40-float runs: wv2[bg][t][h0*2 .. h0*2+39]
  const int sub = b / 40;         // 0..5 (6 bg per iter), b<240 active
  const int idx = b % 40;         // h = h0 + idx/2, j = idx&1
#pragma unroll 1
  for (int it = 0; it < 22; ++it) {
    const int bg = it * 6 + sub;
    if (b < 240 && bg < NBG) {
      wv2[((size_t)bg * TT + t) * 1024 + h0 * 2 + idx] =
          al[idx >> 1][2 * bg + (idx & 1)];
    }
  }
}

// ---------------- Phase B dot: chunk-blocked software-pipelined panel dot ----
// Strict ascending k (chunks ascending, pairs ascending, k = 2p then 2p+1),
// mul-then-add (no FMA: r arbitrary). U loads: 4 dwordx4/chunk, double-buffered.
// ubase = (char*)UTPC + h*64; chunk c bytes at ubase + c*32768.
template <int CBASE, int NCHUNK, int REM>
__device__ __forceinline__ f2v dot_panel(const char* __restrict__ ubase,
                                         const float4* __restrict__ rq_cp) {
#pragma clang fp contract(off)
  float4 A0, A1, A2, A3, B0, B1, B2, B3;
  {
    const float4* s = (const float4*)(ubase + (size_t)CBASE * 32768);
    A0 = s[0]; A1 = s[1]; A2 = s[2]; A3 = s[3];
  }
  f2v acc; acc.x = 0.0f; acc.y = 0.0f;
#pragma unroll 1
  for (int c = 0; c < NCHUNK; ++c) {
    const float4* ns = (const float4*)(ubase + (size_t)(CBASE + c + 1) * 32768);
    if (c + 1 < NCHUNK) { B0 = ns[0]; B1 = ns[1]; B2 = ns[2]; B3 = ns[3]; }
    else if (REM > 0)   { B0 = ns[0]; }
    const int pb = (CBASE + c) * 8;
#define PAIRSTEP(AR, S0, S1, i) { \
      const float4 r4 = rq_cp[2 * (pb + (i))]; \
      f2v ux; ux.x = AR.S0; ux.y = AR.S0; \
      f2v uy; uy.x = AR.S1; uy.y = AR.S1; \
      f2v r0; r0.x = r4.x; r0.y = r4.y; \
      f2v r1; r1.x = r4.z; r1.y = r4.w; \
      acc = acc + ux * r0; \
      acc = acc + uy * r1; }
    PAIRSTEP(A0, x, y, 0) PAIRSTEP(A0, z, w, 1)
    PAIRSTEP(A1, x, y, 2) PAIRSTEP(A1, z, w, 3)
    PAIRSTEP(A2, x, y, 4) PAIRSTEP(A2, z, w, 5)
    PAIRSTEP(A3, x, y, 6) PAIRSTEP(A3, z, w, 7)
#undef PAIRSTEP
    A0 = B0; A1 = B1; A2 = B2; A3 = B3;
  }
  if (REM > 0) {        // REM == 2: pairs pb, pb+1 live in A0 (xy, zw)
    const int pb = (CBASE + NCHUNK) * 8;
    {
      const float4 r4 = rq_cp[2 * pb];
      f2v ux; ux.x = A0.x; ux.y = A0.x;
      f2v uy; uy.x = A0.y; uy.y = A0.y;
      f2v r0; r0.x = r4.x; r0.y = r4.y;
      f2v r1; r1.x = r4.z; r1.y = r4.w;
      acc = acc + ux * r0;
      acc = acc + uy * r1;
    }
    {
      const float4 r4 = rq_cp[2 * (pb + 1)];
      f2v ux; ux.x = A0.z; ux.y = A0.z;
      f2v uy; uy.x = A0.w; uy.y = A0.w;
      f2v r0; r0.x = r4.x; r0.y = r4.y;
      f2v r1; r1.x = r4.z; r1.y = r4.w;
      acc = acc + ux * r0;
      acc = acc + uy * r1;
    }
  }
  return acc;
}

// ---------------- Phase B: quad-split recurrence ---------------------------
// 256 blocks: bid = q*64 + cg. 512 threads: pan = tid>>8, idx = tid&255,
// cp = idx&1 (bg = 2cg+cp), hl = idx>>1 (h = q*128+hl). Adjacent lanes share
// (pan,hl), differ in cp -> U loads broadcast-merge; r pair-interleaved in
// LDS (zero conflicts). Panels: pan0 chunks 0..17 (k 0..287), pan1 chunks
// 18..30 + 2 pairs (k 288..499) — the Eigen kc=288 split.
__global__ __launch_bounds__(512) void hidden_quad(
    const float2* __restrict__ UTPC, const float* __restrict__ b_h,
    const float* __restrict__ b_init, const uint32_t* __restrict__ keys,
    const float* __restrict__ wv2, uint32_t* __restrict__ hbw,
    unsigned long long* __restrict__ exch, uint32_t* __restrict__ prog) {
#pragma clang fp contract(off)
  const int tid = threadIdx.x;
  const int pan = tid >> 8;           // wave-uniform
  const int idx = tid & 255;
  const int cp = idx & 1;
  const int hl = idx >> 1;            // 0..127
  const int bid = (int)blockIdx.x;
  const int cg = bid & 63;
  const int q = bid >> 6;
  const int h = q * 128 + hl;
  const int hs = (h < NH) ? h : 0;
  const int bg = 2 * cg + cp;
  const int b0 = 2 * bg;              // = 4cg + 2cp

  __shared__ __align__(16) float4 rq[512];    // [pair p][cp], 250*2 used
  __shared__ f2v ps_l[256];           // [hl][cp] panel-1 partials
  __shared__ f2v u_l[256];            // [hl][cp] uniforms
  __shared__ uint32_t keyl[2 * TT];

  keyl[tid] = keys[4 * (tid >> 1) + (tid & 1)];
  if (pan == 0) {                     // zero both halves once (r_lag(0) = 0)
    float4 z; z.x = 0.0f; z.y = 0.0f; z.z = 0.0f; z.w = 0.0f;
    rq[idx] = z; rq[256 + idx] = z;
  }
  const float bh = b_h[hs], bi = b_init[hs];
  const char* __restrict__ ubase = (const char*)UTPC + (size_t)h * 64;
  f2v* __restrict__ rw = (f2v*)rq;    // f2v view: index (h>>1)*4 + cp*2 + (h&1)
  const float4* __restrict__ rq_cp = rq + cp;
  // partner bids (other quarters, same cg -> same XCD residue mod 8)
  const int p1 = (((q + 1) & 3) << 6) | cg;
  const int p2 = (((q + 2) & 3) << 6) | cg;
  const int p3 = (((q + 3) & 3) << 6) | cg;
  __syncthreads();

#pragma unroll 1
  for (int t = 0; t < TT; ++t) {
    f2v wvp; wvp.x = 0.0f; wvp.y = 0.0f;
    f2v a;
    if (pan == 0) {
      wvp = *(const f2v*)&wv2[((size_t)bg * TT + t) * 1024 + h * 2];
      a = dot_panel<0, 18, 0>(ubase, rq_cp);    // k = 0..287
    } else {
      a = dot_panel<18, 13, 2>(ubase, rq_cp);   // k = 288..499
      ps_l[hl * 2 + cp] = a;
      const uint32_t k0 = keyl[2 * t], k1 = keyl[2 * t + 1];
      f2v u;
      u.x = jax_uniform(draw_bits(k0, k1, (uint32_t)(h * BB + b0)));
      u.y = jax_uniform(draw_bits(k0, k1, (uint32_t)(h * BB + b0 + 1)));
      u_l[hl * 2 + cp] = u;
    }
    __syncthreads();

    if (pan == 0) {
      const f2v ps = ps_l[hl * 2 + cp];
      const float acc0 = a.x + ps.x;          // == (0+panel0)+panel1
      const float acc1 = a.y + ps.y;
      const float bias = (t == 0) ? bi : bh;
      const float pre0 = (wvp.x + acc0) + bias;   // reference order
      const float pre1 = (wvp.y + acc1) + bias;
      const float pp0 = xla_sigmoid(pre0);
      const float pp1 = xla_sigmoid(pre1);
      f2v pv; pv.x = pp0; pv.y = pp1;
      rw[(h >> 1) * 4 + cp * 2 + (h & 1)] = pv;   // own quarter, pair-interleaved
      if (t != TT - 1) {
        __hip_atomic_store(&exch[((size_t)bid * 2 + (t & 1)) * 256 + idx],
                           __builtin_bit_cast(unsigned long long, pv),
                           __ATOMIC_RELAXED, __HIP_MEMORY_SCOPE_AGENT);
      }
      const f2v u = u_l[hl * 2 + cp];
      const bool hm0 = u.x < pp0;
      const bool hm1 = u.y < pp1;
      // lane-interleaved masks: even bits = cp0, odd = cp1
      const unsigned long long m0 = __ballot(hm0);
      const unsigned long long m1 = __ballot(hm1);
      const uint32_t e0 = extract_even(m0);        // (bg=2cg,   col 0)
      const uint32_t o0 = extract_even(m0 >> 1);   // (bg=2cg+1, col 0)
      const uint32_t e1 = extract_even(m1);        // (bg=2cg,   col 1)
      const uint32_t o1 = extract_even(m1 >> 1);   // (bg=2cg+1, col 1)
      if ((tid & 63) == 0) {
        uint4 w4; w4.x = e0; w4.y = e1; w4.z = o0; w4.w = o1;
        *(uint4*)&hbw[(size_t)(h >> 5) * (TT * BB) + (size_t)t * BB + 4 * cg] = w4;
      }
    }
    if (t == TT - 1) break;

    // barrier drains outbox atomics (vmcnt) + rq own-quarter writes
    __syncthreads();
    if (tid == 0)
      __hip_atomic_store(&prog[bid * 32], (uint32_t)(t + 1),
                         __ATOMIC_RELAXED, __HIP_MEMORY_SCOPE_AGENT);
    if (pan == 1) {
      const uint32_t tgt = (uint32_t)(t + 1);
      while (__hip_atomic_load(&prog[p1 * 32], __ATOMIC_RELAXED,
                               __HIP_MEMORY_SCOPE_AGENT) < tgt ||
             __hip_atomic_load(&prog[p2 * 32], __ATOMIC_RELAXED,
                               __HIP_MEMORY_SCOPE_AGENT) < tgt ||
             __hip_atomic_load(&prog[p3 * 32], __ATOMIC_RELAXED,
                               __HIP_MEMORY_SCOPE_AGENT) < tgt)
        __builtin_amdgcn_s_sleep(4);
      const int par[3] = {p1, p2, p3};
#pragma unroll
      for (int i = 0; i < 3; ++i) {
        const int pq = (q + 1 + i) & 3;
        unsigned long long w = __hip_atomic_load(
            &exch[((size_t)par[i] * 2 + (t & 1)) * 256 + idx],
            __ATOMIC_RELAXED, __HIP_MEMORY_SCOPE_AGENT);
        const int hh = pq * 128 + hl;
        rw[(hh >> 1) * 4 + cp * 2 + (hh & 1)] = __builtin_bit_cast(f2v, w);
      }
    }
    __syncthreads();
  }
}

// ---------------- Phase E: expand packed h bits -> out_r floats ----------------
__global__ __launch_bounds__(256) void expand_r(
    const uint32_t* __restrict__ hbw, float* __restrict__ out_r) {
  const int h = blockIdx.x;           // 0..499
  const int b = threadIdx.x;
  const uint32_t sh = (uint32_t)(h & 31);
  const uint32_t* src = hbw + (size_t)(h >> 5) * (TT * BB);
  float* dst = out_r + (size_t)h * (TT * BB);
#pragma unroll 4
  for (int t = 0; t < TT; ++t) {
    uint32_t w = src[t * BB + b];
    dst[t * BB + b] = (float)((w >> sh) & 1u);
  }
}

// ---------------- Phase C: all visible steps; h read from out_r ----------------
// fmaf(w, h, s) == s + w*h bit-exactly because h in {0,1}.
#define IT_C 16   // 784/16 = 49 i-tiles; grid 49*256 = 12544
__global__ __launch_bounds__(256, 4) void visible_big(
    const float* __restrict__ WT, const float* __restrict__ b_v,
    const uint32_t* __restrict__ keys, const float* __restrict__ hplane,
    float* __restrict__ out_v) {
#pragma clang fp contract(off)
  const int b = threadIdx.x;
  const int bid = (int)blockIdx.x;      // 0..12543
  const int xcd = bid & 7;
  const int slot = bid >> 3;            // 0..1567
  const int t = (slot / 49) * 8 + xcd;  // same-t blocks land on one XCD
  const int i0 = (slot % 49) * IT_C;
  const float* hcol = hplane + (size_t)t * BB + b;  // element k: hcol[k * TT*BB]

  float acc[IT_C];
#pragma unroll
  for (int r = 0; r < IT_C; ++r) acc[r] = 0.0f;

  const int pb[3] = {0, 288, 500};
#pragma unroll 1
  for (int p = 0; p < 2; ++p) {
    float ps[IT_C];
#pragma unroll
    for (int r = 0; r < IT_C; ++r) ps[r] = 0.0f;
    const int k0 = pb[p], k1 = pb[p + 1];
#pragma unroll 8
    for (int k = k0; k < k1; ++k) {
      float hh = hcol[(size_t)k * (TT * BB)];
#pragma unroll
      for (int r = 0; r < IT_C; ++r)
        ps[r] = __builtin_fmaf(WT[(size_t)(i0 + r) * NH + k], hh, ps[r]);
    }
#pragma unroll
    for (int r = 0; r < IT_C; ++r) acc[r] = acc[r] + ps[r];
  }

  const uint32_t key0 = keys[4 * t + 2], key1 = keys[4 * t + 3];
#pragma unroll
  for (int r = 0; r < IT_C; ++r) {
    const int i = i0 + r;
    float pre = acc[r] + b_v[i];
    float p = xla_sigmoid(pre);
    uint32_t j = (uint32_t)(i * BB + b);
    float u = jax_uniform(draw_bits(key0, key1, j));
    out_v[(size_t)i * (TT * BB) + (size_t)t * BB + b] = (u < p) ? 1.0f : 0.0f;
  }
}

extern "C" void kernel_launch(void* const* d_in, const int* in_sizes, int n_in,
                              void* d_out, int out_size, void* d_ws, size_t ws_size,
                              hipStream_t stream) {
  const float* v      = (const float*)d_in[0];
  const float* W      = (const float*)d_in[1];
  const float* U      = (const float*)d_in[2];
  const float* b_h    = (const float*)d_in[3];
  const float* b_v    = (const float*)d_in[4];
  const float* b_init = (const float*)d_in[5];

  float* out_v = (float*)d_out;                       // (784,256,256) = 205.5 MB
  float* out_r = out_v + (size_t)NV * TT * BB;        // (500,256,256) = 131 MB

  // Staging inside the out_v region (dead before phase C overwrites out_v):
  //   wv2:  134.2 MB at offset 0
  //   exch: 256 blocks x 2 slots x 256 u64 = 1 MB after wv2
  //   prog: 256 x 32 u32 (128B-spaced) after exch
  // UTPC (1 MB, 32 chunks x 512 h x 8 pairs) at head of out_r region
  // (dead before phase E overwrites out_r).
  float* wv2 = out_v;
  unsigned long long* exch =
      (unsigned long long*)(out_v + (size_t)NBG * TT * 1024);
  uint32_t* prog = (uint32_t*)(exch + (size_t)256 * 2 * 256);
  float2* UTPC = (float2*)out_r;

  // ws: WT (1.57 MB) + keys (4 KB) + hbw (4.19 MB)
  float* WT = (float*)d_ws;
  uint32_t* keys = (uint32_t*)(WT + (size_t)NV * NH);
  uint32_t* hbw = keys + TT * 4;   // [16][256][256] u32

  hipMemsetAsync(prog, 0, 256 * 32 * sizeof(uint32_t), stream);
  init_keys<<<1, 256, 0, stream>>>(keys);
  wt_kernel<<<NV, 256, 0, stream>>>(W, WT);
  ut_kernel<<<250, 512, 0, stream>>>(U, UTPC);

  wv_gemm<<<25 * TT, 256, 0, stream>>>(v, W, wv2);

  hidden_quad<<<256, 512, 0, stream>>>(UTPC, b_h, b_init, keys, wv2, hbw,
                                       exch, prog);

  expand_r<<<NH, 256, 0, stream>>>(hbw, out_r);

  visible_big<<<49 * TT, 256, 0, stream>>>(WT, b_v, keys, out_r, out_v);
}

// Round 16
// 4254.185 us; speedup vs baseline: 1.1417x; 1.0584x over previous
//
#include <hip/hip_runtime.h>
#include <stdint.h>

// RTRBM CD-1: bit-exact replication of the JAX-CPU reference.
// Phase A: wv_gemm — XCD-swizzled, HT_A=20, launch_bounds(256,4) (r12).
// Phase B: hidden_quad — quad h-split, cp-interleaved lanes, pair-interleaved
//          r in LDS (0 conflicts), chunk-blocked U (r15). NEW (r16):
//          depth-2 U prefetch; single-lane polls (readfirstlane broadcast);
//          pulls split pan0/pan1; hbw pack overlapped with partner arrival.
// Phase E: expand bits -> out_r floats.
// Phase C: visible_big — spill fix + XCD swizzle (r12).
// Sizes: V=784, H=500, T=256, B=256. RNG: threefry partitionable.
// Eigen MT blocking (AVX no-FMA jaxlib): kc=288. K=784 -> [288,288,208]; K=500 -> [288,212].
#define NV 784
#define NH 500
#define TT 256
#define BB 256
#define NBG 128   // b-pairs

typedef float f2v __attribute__((ext_vector_type(2)));

// ---------------- threefry2x32 (JAX PRNG), exact ----------------
__device__ __forceinline__ void tf2x32(uint32_t ks0, uint32_t ks1,
                                       uint32_t x0, uint32_t x1,
                                       uint32_t& y0, uint32_t& y1) {
  uint32_t ks2 = ks0 ^ ks1 ^ 0x1BD11BDAu;
  x0 += ks0; x1 += ks1;
#define TFROT(r) { x0 += x1; x1 = (x1 << (r)) | (x1 >> (32 - (r))); x1 ^= x0; }
  TFROT(13) TFROT(15) TFROT(26) TFROT(6)
  x0 += ks1; x1 += ks2 + 1u;
  TFROT(17) TFROT(29) TFROT(16) TFROT(24)
  x0 += ks2; x1 += ks0 + 2u;
  TFROT(13) TFROT(15) TFROT(26) TFROT(6)
  x0 += ks0; x1 += ks1 + 3u;
  TFROT(17) TFROT(29) TFROT(16) TFROT(24)
  x0 += ks1; x1 += ks2 + 4u;
  TFROT(13) TFROT(15) TFROT(26) TFROT(6)
  x0 += ks2; x1 += ks0 + 5u;
#undef TFROT
  y0 = x0; y1 = x1;
}

__device__ __forceinline__ float jax_uniform(uint32_t bits) {
#pragma clang fp contract(off)
  float f = __uint_as_float((bits >> 9) | 0x3F800000u);
  return f - 1.0f;
}

// PARTITIONABLE random_bits, 32-bit: bits[j] = y0 ^ y1 of threefry(key; 0, j)
__device__ __forceinline__ uint32_t draw_bits(uint32_t k0, uint32_t k1,
                                              uint32_t j) {
  uint32_t y0, y1;
  tf2x32(k0, k1, 0u, j, y0, y1);
  return y0 ^ y1;
}

// ---------------- XLA CPU exp (Cephes/Eigen poly, no FMA) ----------------
__device__ __forceinline__ float xla_expf(float x) {
#pragma clang fp contract(off)
  float xc = fminf(fmaxf(x, -88.3762626647949f), 88.3762626647950f);
  float fx = floorf(xc * 1.44269504088896341f + 0.5f);
  float tmp = 0.693359375f * fx;
  float z = -2.12194440e-4f * fx;
  float xr = xc - tmp;
  xr = xr - z;
  z = xr * xr;
  float y = xr * 1.9875691500e-4f + 1.3981999507e-3f;
  y = y * xr + 8.3334519073e-3f;
  y = y * xr + 4.1665795894e-2f;
  y = y * xr + 1.6666665459e-1f;
  y = y * xr + 5.0000001201e-1f;
  y = y * z + xr;
  y = 1.0f + y;
  int e = (int)fx;
  float pow2 = __int_as_float((uint32_t)(e + 127) << 23);
  return y * pow2;
}

__device__ __forceinline__ float xla_sigmoid(float x) {
#pragma clang fp contract(off)
  float e = xla_expf(-x);
  float d = 1.0f + e;
  return 1.0f / d;
}

// even-bit compress: 64-bit mask -> 32 bits taken from even lane positions
__device__ __forceinline__ uint32_t extract_even(unsigned long long x) {
  x &= 0x5555555555555555ull;
  x = (x ^ (x >> 1)) & 0x3333333333333333ull;
  x = (x ^ (x >> 2)) & 0x0F0F0F0F0F0F0F0Full;
  x = (x ^ (x >> 4)) & 0x00FF00FF00FF00FFull;
  x = (x ^ (x >> 8)) & 0x0000FFFF0000FFFFull;
  x = (x ^ (x >> 16)) & 0x00000000FFFFFFFFull;
  return (uint32_t)x;
}

// ---------------- key derivation (PARTITIONABLE split) ----------------
__global__ void init_keys(uint32_t* __restrict__ keys /* [256][4] */) {
  int t = threadIdx.x;
  if (t >= TT) return;
  uint32_t kt0, kt1;
  tf2x32(0u, 123u, 0u, (uint32_t)t, kt0, kt1);
  uint32_t a0, a1, b0, b1;
  tf2x32(kt0, kt1, 0u, 0u, a0, a1);  // k1 (hidden)
  tf2x32(kt0, kt1, 0u, 1u, b0, b1);  // k2 (visible)
  keys[4 * t + 0] = a0;
  keys[4 * t + 1] = a1;
  keys[4 * t + 2] = b0;
  keys[4 * t + 3] = b1;
}

// ---------------- W transpose: WT[i][k] = W[k][i] ----------------
__global__ __launch_bounds__(256) void wt_kernel(const float* __restrict__ W,
                                                 float* __restrict__ WT) {
  const int i = blockIdx.x;           // 0..783
  for (int k = threadIdx.x; k < NH; k += 256)
    WT[(size_t)i * NH + k] = W[(size_t)k * NV + i];
}

// ---------------- U chunk-blocked transpose ----------------
// UTPC element (c, h, i) at ((c*512 + h)*8 + i) float2 = (U[h][2p], U[h][2p+1]),
// p = 8c+i. Per-thread chunk = 64 contiguous bytes; h-lanes stride 64B.
__global__ __launch_bounds__(512) void ut_kernel(const float* __restrict__ U,
                                                 float2* __restrict__ UTPC) {
  const int p = blockIdx.x;           // 0..249
  const int h = threadIdx.x;          // 0..511
  float2 w;
  if (h < NH) {
    w.x = U[(size_t)h * NH + 2 * p];
    w.y = U[(size_t)h * NH + 2 * p + 1];
  } else {
    w.x = 0.0f; w.y = 0.0f;
  }
  UTPC[((size_t)(p >> 3) * 512 + h) * 8 + (p & 7)] = w;
}

// ---------------- Phase A: WV2[bg][t][h][2] = (W @ v_t)[h][b] ----------------
// fmaf(w, x, s) == s + w*x bit-exactly because x in {0,1} (w*x exact).
#define HT_A 20   // 500/20 = 25 h-tiles per t; grid 25*256 = 6400
__global__ __launch_bounds__(256, 4) void wv_gemm(
    const float* __restrict__ v, const float* __restrict__ W,
    float* __restrict__ wv2) {
#pragma clang fp contract(off)
  const int b = threadIdx.x;
  const int bid = (int)blockIdx.x;      // 0..6399
  const int xcd = bid & 7;
  const int slot = bid >> 3;            // 0..799
  const int t = (slot / 25) * 8 + xcd;  // same-t blocks land on one XCD
  const int h0 = (slot % 25) * HT_A;
  const float* vcol = v + (size_t)t * BB + b;   // element k: vcol[k * TT*BB]

  float acc[HT_A];
#pragma unroll
  for (int r = 0; r < HT_A; ++r) acc[r] = 0.0f;

  const int pb[4] = {0, 288, 576, 784};   // kc=288 panels
#pragma unroll 1
  for (int p = 0; p < 3; ++p) {
    float ps[HT_A];
#pragma unroll
    for (int r = 0; r < HT_A; ++r) ps[r] = 0.0f;
    const int k0 = pb[p], k1 = pb[p + 1];
#pragma unroll 8
    for (int k = k0; k < k1; ++k) {
      float x = vcol[(size_t)k * (TT * BB)];
#pragma unroll
      for (int r = 0; r < HT_A; ++r)
        ps[r] = __builtin_fmaf(W[(size_t)(h0 + r) * NV + k], x, ps[r]);
    }
#pragma unroll
    for (int r = 0; r < HT_A; ++r) acc[r] = acc[r] + ps[r];
  }

  // LDS transpose (padded)
  __shared__ float al[HT_A][BB + 1];
#pragma unroll
  for (int r = 0; r < HT_A; ++r) al[r][b] = acc[r];
  __syncthreads();

  // write 40-float runs: wv2[bg][t][h0*2 .. h0*2+39]
  const int sub = b / 40;         // 0..5 (6 bg per iter), b<240 active
  const int idx = b % 40;         // h = h0 + idx/2, j = idx&1
#pragma unroll 1
  for (int it = 0; it < 22; ++it) {
    const int bg = it * 6 + sub;
    if (b < 240 && bg < NBG) {
      wv2[((size_t)bg * TT + t) * 1024 + h0 * 2 + idx] =
          al[idx >> 1][2 * bg + (idx & 1)];
    }
  }
}

// ---------------- Phase B dot: depth-2 pipelined chunk-blocked panel dot ----
// Strict ascending k (chunks ascending, pairs ascending, k = 2p then 2p+1),
// mul-then-add (no FMA: r arbitrary). U loads: 4 dwordx4/chunk, 2-deep
// register pipeline (A = current, B = +1, C = +2), all statically indexed.
template <int CBASE, int NCHUNK, int REM>
__device__ __forceinline__ f2v dot_panel(const char* __restrict__ ubase,
                                         const float4* __restrict__ rq_cp) {
#pragma clang fp contract(off)
  float4 A0, A1, A2, A3, B0, B1, B2, B3, C0, C1, C2, C3;
  {
    const float4* s = (const float4*)(ubase + (size_t)CBASE * 32768);
    A0 = s[0]; A1 = s[1]; A2 = s[2]; A3 = s[3];
  }
  B0 = A0; B1 = A1; B2 = A2; B3 = A3;
  if (NCHUNK > 1) {
    const float4* s = (const float4*)(ubase + (size_t)(CBASE + 1) * 32768);
    B0 = s[0]; B1 = s[1]; B2 = s[2]; B3 = s[3];
  } else if (REM > 0) {
    const float4* s = (const float4*)(ubase + (size_t)(CBASE + 1) * 32768);
    B0 = s[0];
  }
  C0 = A0; C1 = A1; C2 = A2; C3 = A3;
  f2v acc; acc.x = 0.0f; acc.y = 0.0f;
#pragma unroll 1
  for (int c = 0; c < NCHUNK; ++c) {
    if (c + 2 < NCHUNK) {
      const float4* ns = (const float4*)(ubase + (size_t)(CBASE + c + 2) * 32768);
      C0 = ns[0]; C1 = ns[1]; C2 = ns[2]; C3 = ns[3];
    } else if (c + 2 == NCHUNK && REM > 0) {
      const float4* ns = (const float4*)(ubase + (size_t)(CBASE + c + 2) * 32768);
      C0 = ns[0];
    }
    const int pb = (CBASE + c) * 8;
#define PAIRSTEP(AR, S0, S1, i) { \
      const float4 r4 = rq_cp[2 * (pb + (i))]; \
      f2v ux; ux.x = AR.S0; ux.y = AR.S0; \
      f2v uy; uy.x = AR.S1; uy.y = AR.S1; \
      f2v r0; r0.x = r4.x; r0.y = r4.y; \
      f2v r1; r1.x = r4.z; r1.y = r4.w; \
      acc = acc + ux * r0; \
      acc = acc + uy * r1; }
    PAIRSTEP(A0, x, y, 0) PAIRSTEP(A0, z, w, 1)
    PAIRSTEP(A1, x, y, 2) PAIRSTEP(A1, z, w, 3)
    PAIRSTEP(A2, x, y, 4) PAIRSTEP(A2, z, w, 5)
    PAIRSTEP(A3, x, y, 6) PAIRSTEP(A3, z, w, 7)
#undef PAIRSTEP
    A0 = B0; A1 = B1; A2 = B2; A3 = B3;
    B0 = C0; B1 = C1; B2 = C2; B3 = C3;
  }
  if (REM > 0) {        // REM == 2: pairs pb, pb+1 live in A0 (xy, zw)
    const int pb = (CBASE + NCHUNK) * 8;
    {
      const float4 r4 = rq_cp[2 * pb];
      f2v ux; ux.x = A0.x; ux.y = A0.x;
      f2v uy; uy.x = A0.y; uy.y = A0.y;
      f2v r0; r0.x = r4.x; r0.y = r4.y;
      f2v r1; r1.x = r4.z; r1.y = r4.w;
      acc = acc + ux * r0;
      acc = acc + uy * r1;
    }
    {
      const float4 r4 = rq_cp[2 * (pb + 1)];
      f2v ux; ux.x = A0.z; ux.y = A0.z;
      f2v uy; uy.x = A0.w; uy.y = A0.w;
      f2v r0; r0.x = r4.x; r0.y = r4.y;
      f2v r1; r1.x = r4.z; r1.y = r4.w;
      acc = acc + ux * r0;
      acc = acc + uy * r1;
    }
  }
  return acc;
}

// single-lane poll: lane 0 of each wave loads, readfirstlane broadcasts.
__device__ __forceinline__ void poll_one(const uint32_t* __restrict__ prog,
                                         int p, uint32_t tgt, int tid) {
  for (;;) {
    uint32_t v = 0;
    if ((tid & 63) == 0)
      v = __hip_atomic_load(&prog[p * 32], __ATOMIC_RELAXED,
                            __HIP_MEMORY_SCOPE_AGENT);
    v = __builtin_amdgcn_readfirstlane(v);
    if (v >= tgt) break;
    __builtin_amdgcn_s_sleep(1);
  }
}

__device__ __forceinline__ void poll_two(const uint32_t* __restrict__ prog,
                                         int pa, int pb2, uint32_t tgt, int tid) {
  for (;;) {
    uint32_t va = 0, vb = 0;
    if ((tid & 63) == 0) {
      va = __hip_atomic_load(&prog[pa * 32], __ATOMIC_RELAXED,
                             __HIP_MEMORY_SCOPE_AGENT);
      vb = __hip_atomic_load(&prog[pb2 * 32], __ATOMIC_RELAXED,
                             __HIP_MEMORY_SCOPE_AGENT);
    }
    va = __builtin_amdgcn_readfirstlane(va);
    vb = __builtin_amdgcn_readfirstlane(vb);
    if (va >= tgt && vb >= tgt) break;
    __builtin_amdgcn_s_sleep(1);
  }
}

// ---------------- Phase B: quad-split recurrence ---------------------------
// 256 blocks: bid = q*64 + cg. 512 threads: pan = tid>>8, idx = tid&255,
// cp = idx&1 (bg = 2cg+cp), hl = idx>>1 (h = q*128+hl). Adjacent lanes share
// (pan,hl), differ in cp -> U loads broadcast-merge; r pair-interleaved in
// LDS (zero conflicts). Panels: pan0 chunks 0..17 (k 0..287), pan1 chunks
// 18..30 + 2 pairs (k 288..499) — the Eigen kc=288 split.
// Exchange tail (r16): pan0 polls/pulls partner q+1; pan1 polls/pulls q+2,q+3;
// hbw pack overlaps the partner-arrival window.
__global__ __launch_bounds__(512) void hidden_quad(
    const float2* __restrict__ UTPC, const float* __restrict__ b_h,
    const float* __restrict__ b_init, const uint32_t* __restrict__ keys,
    const float* __restrict__ wv2, uint32_t* __restrict__ hbw,
    unsigned long long* __restrict__ exch, uint32_t* __restrict__ prog) {
#pragma clang fp contract(off)
  const int tid = threadIdx.x;
  const int pan = tid >> 8;           // wave-uniform
  const int idx = tid & 255;
  const int cp = idx & 1;
  const int hl = idx >> 1;            // 0..127
  const int bid = (int)blockIdx.x;
  const int cg = bid & 63;
  const int q = bid >> 6;
  const int h = q * 128 + hl;
  const int hs = (h < NH) ? h : 0;
  const int bg = 2 * cg + cp;
  const int b0 = 2 * bg;              // = 4cg + 2cp

  __shared__ __align__(16) float4 rq[512];    // [pair p][cp], 250*2 used
  __shared__ f2v ps_l[256];           // [hl][cp] panel-1 partials
  __shared__ f2v u_l[256];            // [hl][cp] uniforms
  __shared__ uint32_t keyl[2 * TT];

  keyl[tid] = keys[4 * (tid >> 1) + (tid & 1)];
  if (pan == 0) {                     // zero both halves once (r_lag(0) = 0)
    float4 z; z.x = 0.0f; z.y = 0.0f; z.z = 0.0f; z.w = 0.0f;
    rq[idx] = z; rq[256 + idx] = z;
  }
  const float bh = b_h[hs], bi = b_init[hs];
  const char* __restrict__ ubase = (const char*)UTPC + (size_t)h * 64;
  f2v* __restrict__ rw = (f2v*)rq;    // f2v view: index (h>>1)*4 + cp*2 + (h&1)
  const float4* __restrict__ rq_cp = rq + cp;
  // partner bids (other quarters, same cg -> same XCD residue mod 8)
  const int p1 = (((q + 1) & 3) << 6) | cg;
  const int p2 = (((q + 2) & 3) << 6) | cg;
  const int p3 = (((q + 3) & 3) << 6) | cg;
  __syncthreads();

#pragma unroll 1
  for (int t = 0; t < TT; ++t) {
    f2v wvp; wvp.x = 0.0f; wvp.y = 0.0f;
    f2v a;
    if (pan == 0) {
      wvp = *(const f2v*)&wv2[((size_t)bg * TT + t) * 1024 + h * 2];
      a = dot_panel<0, 18, 0>(ubase, rq_cp);    // k = 0..287
    } else {
      a = dot_panel<18, 13, 2>(ubase, rq_cp);   // k = 288..499
      ps_l[hl * 2 + cp] = a;
      const uint32_t k0 = keyl[2 * t], k1 = keyl[2 * t + 1];
      f2v u;
      u.x = jax_uniform(draw_bits(k0, k1, (uint32_t)(h * BB + b0)));
      u.y = jax_uniform(draw_bits(k0, k1, (uint32_t)(h * BB + b0 + 1)));
      u_l[hl * 2 + cp] = u;
    }
    __syncthreads();   // barrier 1: ps_l/u_l ready

    bool hm0 = false, hm1 = false;
    if (pan == 0) {
      const f2v ps = ps_l[hl * 2 + cp];
      const float acc0 = a.x + ps.x;          // == (0+panel0)+panel1
      const float acc1 = a.y + ps.y;
      const float bias = (t == 0) ? bi : bh;
      const float pre0 = (wvp.x + acc0) + bias;   // reference order
      const float pre1 = (wvp.y + acc1) + bias;
      const float pp0 = xla_sigmoid(pre0);
      const float pp1 = xla_sigmoid(pre1);
      f2v pv; pv.x = pp0; pv.y = pp1;
      rw[(h >> 1) * 4 + cp * 2 + (h & 1)] = pv;   // own quarter, pair-interleaved
      if (t != TT - 1) {
        __hip_atomic_store(&exch[((size_t)bid * 2 + (t & 1)) * 256 + idx],
                           __builtin_bit_cast(unsigned long long, pv),
                           __ATOMIC_RELAXED, __HIP_MEMORY_SCOPE_AGENT);
      }
      const f2v u = u_l[hl * 2 + cp];
      hm0 = u.x < pp0;
      hm1 = u.y < pp1;
    }

    // barrier 2: drains exch atomic stores (vmcnt) + rq own-quarter writes
    __syncthreads();
    const uint32_t tgt = (uint32_t)(t + 1);
    if (tid == 0 && t != TT - 1)
      __hip_atomic_store(&prog[bid * 32], tgt,
                         __ATOMIC_RELAXED, __HIP_MEMORY_SCOPE_AGENT);

    if (pan == 0) {
      // hbw pack — overlaps partners' arrival window
      const unsigned long long m0 = __ballot(hm0);
      const unsigned long long m1 = __ballot(hm1);
      const uint32_t e0 = extract_even(m0);        // (bg=2cg,   col 0)
      const uint32_t o0 = extract_even(m0 >> 1);   // (bg=2cg+1, col 0)
      const uint32_t e1 = extract_even(m1);        // (bg=2cg,   col 1)
      const uint32_t o1 = extract_even(m1 >> 1);   // (bg=2cg+1, col 1)
      if ((tid & 63) == 0) {
        uint4 w4; w4.x = e0; w4.y = e1; w4.z = o0; w4.w = o1;
        *(uint4*)&hbw[(size_t)(h >> 5) * (TT * BB) + (size_t)t * BB + 4 * cg] = w4;
      }
    }
    if (t == TT - 1) break;

    if (pan == 0) {
      // pull partner q+1's quarter
      poll_one(prog, p1, tgt, tid);
      unsigned long long w = __hip_atomic_load(
          &exch[((size_t)p1 * 2 + (t & 1)) * 256 + idx],
          __ATOMIC_RELAXED, __HIP_MEMORY_SCOPE_AGENT);
      const int hh = (((q + 1) & 3) * 128) + hl;
      rw[(hh >> 1) * 4 + cp * 2 + (hh & 1)] = __builtin_bit_cast(f2v, w);
    } else {
      // pull partner q+2 and q+3 quarters
      poll_two(prog, p2, p3, tgt, tid);
      unsigned long long w2 = __hip_atomic_load(
          &exch[((size_t)p2 * 2 + (t & 1)) * 256 + idx],
          __ATOMIC_RELAXED, __HIP_MEMORY_SCOPE_AGENT);
      unsigned long long w3 = __hip_atomic_load(
          &exch[((size_t)p3 * 2 + (t & 1)) * 256 + idx],
          __ATOMIC_RELAXED, __HIP_MEMORY_SCOPE_AGENT);
      const int hh2 = (((q + 2) & 3) * 128) + hl;
      const int hh3 = (((q + 3) & 3) * 128) + hl;
      rw[(hh2 >> 1) * 4 + cp * 2 + (hh2 & 1)] = __builtin_bit_cast(f2v, w2);
      rw[(hh3 >> 1) * 4 + cp * 2 + (hh3 & 1)] = __builtin_bit_cast(f2v, w3);
    }
    __syncthreads();   // barrier 3: full r ready for next t
  }
}

// ---------------- Phase E: expand packed h bits -> out_r floats ----------------
__global__ __launch_bounds__(256) void expand_r(
    const uint32_t* __restrict__ hbw, float* __restrict__ out_r) {
  const int h = blockIdx.x;           // 0..499
  const int b = threadIdx.x;
  const uint32_t sh = (uint32_t)(h & 31);
  const uint32_t* src = hbw + (size_t)(h >> 5) * (TT * BB);
  float* dst = out_r + (size_t)h * (TT * BB);
#pragma unroll 4
  for (int t = 0; t < TT; ++t) {
    uint32_t w = src[t * BB + b];
    dst[t * BB + b] = (float)((w >> sh) & 1u);
  }
}

// ---------------- Phase C: all visible steps; h read from out_r ----------------
// fmaf(w, h, s) == s + w*h bit-exactly because h in {0,1}.
#define IT_C 16   // 784/16 = 49 i-tiles; grid 49*256 = 12544
__global__ __launch_bounds__(256, 4) void visible_big(
    const float* __restrict__ WT, const float* __restrict__ b_v,
    const uint32_t* __restrict__ keys, const float* __restrict__ hplane,
    float* __restrict__ out_v) {
#pragma clang fp contract(off)
  const int b = threadIdx.x;
  const int bid = (int)blockIdx.x;      // 0..12543
  const int xcd = bid & 7;
  const int slot = bid >> 3;            // 0..1567
  const int t = (slot / 49) * 8 + xcd;  // same-t blocks land on one XCD
  const int i0 = (slot % 49) * IT_C;
  const float* hcol = hplane + (size_t)t * BB + b;  // element k: hcol[k * TT*BB]

  float acc[IT_C];
#pragma unroll
  for (int r = 0; r < IT_C; ++r) acc[r] = 0.0f;

  const int pb[3] = {0, 288, 500};
#pragma unroll 1
  for (int p = 0; p < 2; ++p) {
    float ps[IT_C];
#pragma unroll
    for (int r = 0; r < IT_C; ++r) ps[r] = 0.0f;
    const int k0 = pb[p], k1 = pb[p + 1];
#pragma unroll 8
    for (int k = k0; k < k1; ++k) {
      float hh = hcol[(size_t)k * (TT * BB)];
#pragma unroll
      for (int r = 0; r < IT_C; ++r)
        ps[r] = __builtin_fmaf(WT[(size_t)(i0 + r) * NH + k], hh, ps[r]);
    }
#pragma unroll
    for (int r = 0; r < IT_C; ++r) acc[r] = acc[r] + ps[r];
  }

  const uint32_t key0 = keys[4 * t + 2], key1 = keys[4 * t + 3];
#pragma unroll
  for (int r = 0; r < IT_C; ++r) {
    const int i = i0 + r;
    float pre = acc[r] + b_v[i];
    float p = xla_sigmoid(pre);
    uint32_t j = (uint32_t)(i * BB + b);
    float u = jax_uniform(draw_bits(key0, key1, j));
    out_v[(size_t)i * (TT * BB) + (size_t)t * BB + b] = (u < p) ? 1.0f : 0.0f;
  }
}

extern "C" void kernel_launch(void* const* d_in, const int* in_sizes, int n_in,
                              void* d_out, int out_size, void* d_ws, size_t ws_size,
                              hipStream_t stream) {
  const float* v      = (const float*)d_in[0];
  const float* W      = (const float*)d_in[1];
  const float* U      = (const float*)d_in[2];
  const float* b_h    = (const float*)d_in[3];
  const float* b_v    = (const float*)d_in[4];
  const float* b_init = (const float*)d_in[5];

  float* out_v = (float*)d_out;                       // (784,256,256) = 205.5 MB
  float* out_r = out_v + (size_t)NV * TT * BB;        // (500,256,256) = 131 MB

  // Staging inside the out_v region (dead before phase C overwrites out_v):
  //   wv2:  134.2 MB at offset 0
  //   exch: 256 blocks x 2 slots x 256 u64 = 1 MB after wv2
  //   prog: 256 x 32 u32 (128B-spaced) after exch
  // UTPC (1 MB, 32 chunks x 512 h x 8 pairs) at head of out_r region
  // (dead before phase E overwrites out_r).
  float* wv2 = out_v;
  unsigned long long* exch =
      (unsigned long long*)(out_v + (size_t)NBG * TT * 1024);
  uint32_t* prog = (uint32_t*)(exch + (size_t)256 * 2 * 256);
  float2* UTPC = (float2*)out_r;

  // ws: WT (1.57 MB) + keys (4 KB) + hbw (4.19 MB)
  float* WT = (float*)d_ws;
  uint32_t* keys = (uint32_t*)(WT + (size_t)NV * NH);
  uint32_t* hbw = keys + TT * 4;   // [16][256][256] u32

  hipMemsetAsync(prog, 0, 256 * 32 * sizeof(uint32_t), stream);
  init_keys<<<1, 256, 0, stream>>>(keys);
  wt_kernel<<<NV, 256, 0, stream>>>(W, WT);
  ut_kernel<<<250, 512, 0, stream>>>(U, UTPC);

  wv_gemm<<<25 * TT, 256, 0, stream>>>(v, W, wv2);

  hidden_quad<<<256, 512, 0, stream>>>(UTPC, b_h, b_init, keys, wv2, hbw,
                                       exch, prog);

  expand_r<<<NH, 256, 0, stream>>>(hbw, out_r);

  visible_big<<<49 * TT, 256, 0, stream>>>(WT, b_v, keys, out_r, out_v);
}